// Round 8
// baseline (138.003 us; speedup 1.0000x reference)
//
#include <hip/hip_runtime.h>

#define DD 128   // feature dim
#define SR 72    // LDS row stride in bf16 units (64 + 8 pad, bank-spread)
#define PP 128   // partial tiles per matrix
#define NB (2*PP)
#define KLAST 128            // blocks that perform phase 2
#define POISON 0xAAAAAAAAu   // harness 0xAA byte poison as uint

typedef float f32x4 __attribute__((ext_vector_type(4)));
typedef short s16x8 __attribute__((ext_vector_type(8)));

// ---------------------------------------------------------------------------
// ONE dispatch. 256 blocks x 512 threads.
//
// Phase 1 (identical math to R7, verified absmax 0.0): block p computes the
// partial Gram tile A_p = Xslab^T Xslab (blk<PP) or B_p = Yslab^T Yslab via
// bf16 hi/lo-split MFMA (G = Xh'Xh + Xh'Xl + Xl'Xh). X-blocks fold diag sums
// s1, s2 from the original fp32 registers. All plain stores.
//
// Ticket 1 (deadlock-proof, no grid barrier): all-thread release fence ->
// tid0 atomicAdd on poisoned counter; rank = old - POISON. rank < NB-KLAST:
// block exits. Last KLAST rankers spin (BOUNDED iterations -> clean fail,
// never a hang, if the poison assumption is wrong) until cnt == POISON+NB,
// then block with rank NB-KLAST+c reduces entry-chunk c:
//   S_c = sum_{e in chunk} (sum_p A_p)_e * (sum_p B_p)_e  -> prod[c].
// While <=128 blocks spin, >=128 CUs stay free for the <=127 unfinished
// blocks -> progress guaranteed under any scheduling (1 block/CU capacity).
//
// Ticket 2: last phase-2 finisher reduces 128 prods + 128 ds1/ds2 slots in
// double and writes the scalar loss.
// ---------------------------------------------------------------------------
__global__ __launch_bounds__(512)
void fused_kernel(const float* __restrict__ x, const float* __restrict__ y,
                  float* __restrict__ apart, float* __restrict__ bpart,
                  double* __restrict__ ds1, double* __restrict__ ds2,
                  double* __restrict__ prod,
                  unsigned int* __restrict__ cnt, unsigned int* __restrict__ cnt2,
                  float* __restrict__ out, int N)
{
  const int blk = blockIdx.x;
  const bool isX = blk < PP;
  const int p = isX ? blk : blk - PP;
  const float* __restrict__ src = isX ? x : y;
  const int slab = N / PP;       // 64
  const int row0 = p * slab;

  __shared__ __align__(16) unsigned short sh_hi[DD * SR];  // 18.4 KB
  __shared__ __align__(16) unsigned short sh_lo[DD * SR];  // 18.4 KB
  __shared__ double wred[8][2];
  __shared__ float sA[4][128], sB[4][128];                 // 4 KB (phase 2)
  __shared__ double dcomb[2][3];
  __shared__ unsigned int srank;
  __shared__ int winner;

  const int tid = threadIdx.x;
  const int wave = tid >> 6, lane = tid & 63;
  const int rloc = tid >> 3;     // row within 64-row chunk
  const int fg = tid & 7;        // float4 group within row

  f32x4 acc[8];
#pragma unroll
  for (int t = 0; t < 8; ++t)
#pragma unroll
    for (int k = 0; k < 4; ++k) acc[t][k] = 0.f;

  double s1 = 0.0, s2 = 0.0;

  {
    const float* cb = src + (size_t)row0 * DD;
    const float4* rowp = (const float4*)(cb + rloc * DD);
    float4 v0 = rowp[fg], v1 = rowp[fg + 8], v2 = rowp[fg + 16], v3 = rowp[fg + 24];

    if (isX) {
      const float4* yrp = (const float4*)(y + (size_t)row0 * DD + rloc * DD);
      float4 w0 = yrp[fg], w1 = yrp[fg + 8], w2 = yrp[fg + 16], w3 = yrp[fg + 24];
      float d = v0.x*w0.x + v0.y*w0.y + v0.z*w0.z + v0.w*w0.w
              + v1.x*w1.x + v1.y*w1.y + v1.z*w1.z + v1.w*w1.w
              + v2.x*w2.x + v2.y*w2.y + v2.z*w2.z + v2.w*w2.w
              + v3.x*w3.x + v3.y*w3.y + v3.z*w3.z + v3.w*w3.w;
      d += __shfl_down(d, 4, 8);
      d += __shfl_down(d, 2, 8);
      d += __shfl_down(d, 1, 8);
      if (fg == 0) { s1 += (double)d; s2 += (double)d * (double)d; }
    }

    {
      float vals[16] = {v0.x, v0.y, v0.z, v0.w, v1.x, v1.y, v1.z, v1.w,
                        v2.x, v2.y, v2.z, v2.w, v3.x, v3.y, v3.z, v3.w};
#pragma unroll
      for (int j = 0; j < 4; ++j)
#pragma unroll
        for (int cc = 0; cc < 4; ++cc) {
          const int m = ((fg + (j << 3)) << 2) + cc;
          const float vv = vals[j * 4 + cc];
          const unsigned int b = __float_as_uint(vv);
          const unsigned short hb = (unsigned short)(b >> 16);
          const float hf = __uint_as_float(b & 0xffff0000u);
          const float lf = vv - hf;
          const unsigned short lb = (unsigned short)(__float_as_uint(lf) >> 16);
          sh_hi[m * SR + rloc] = hb;
          sh_lo[m * SR + rloc] = lb;
        }
    }
    __syncthreads();

#pragma unroll
    for (int kb = 0; kb < 64; kb += 32) {
      const int ko = kb + ((lane >> 4) << 3);
      const int arow = (wave * 16 + (lane & 15)) * SR + ko;
      const s16x8 ahi = *(const s16x8*)&sh_hi[arow];
      const s16x8 alo = *(const s16x8*)&sh_lo[arow];
#pragma unroll
      for (int t = 0; t < 8; ++t) {
        const int brow = (t * 16 + (lane & 15)) * SR + ko;
        const s16x8 bhi = *(const s16x8*)&sh_hi[brow];
        const s16x8 blo = *(const s16x8*)&sh_lo[brow];
        acc[t] = __builtin_amdgcn_mfma_f32_16x16x32_bf16(ahi, bhi, acc[t], 0, 0, 0);
        acc[t] = __builtin_amdgcn_mfma_f32_16x16x32_bf16(ahi, blo, acc[t], 0, 0, 0);
        acc[t] = __builtin_amdgcn_mfma_f32_16x16x32_bf16(alo, bhi, acc[t], 0, 0, 0);
      }
    }
  }

  // write private partial tile (C/D layout: col = lane&15, row = (lane>>4)*4+reg)
  float* __restrict__ dst = (isX ? apart : bpart) + (size_t)p * (DD * DD);
  const int col = lane & 15;
  const int rb = (lane >> 4) << 2;
#pragma unroll
  for (int t = 0; t < 8; ++t)
#pragma unroll
    for (int rg = 0; rg < 4; ++rg)
      dst[(wave * 16 + rb + rg) * DD + t * 16 + col] = acc[t][rg];

  if (isX) {
    s1 += __shfl_down(s1, 32, 64); s2 += __shfl_down(s2, 32, 64);
    s1 += __shfl_down(s1, 16, 64); s2 += __shfl_down(s2, 16, 64);
    s1 += __shfl_down(s1, 8, 64);  s2 += __shfl_down(s2, 8, 64);
    if (lane == 0) { wred[wave][0] = s1; wred[wave][1] = s2; }
    __syncthreads();
    if (tid == 0) {
      double t1 = 0.0, t2 = 0.0;
#pragma unroll
      for (int g = 0; g < 8; ++g) { t1 += wred[g][0]; t2 += wred[g][1]; }
      ds1[p] = t1;   // plain stores
      ds2[p] = t2;
    }
  }

  // ---- ticket 1: release all stores, take a rank ----
  __threadfence();      // every thread: order its global stores
  __syncthreads();      // all fences done before tid0's atomic
  if (tid == 0)
    srank = __hip_atomic_fetch_add(cnt, 1u, __ATOMIC_ACQ_REL,
                                   __HIP_MEMORY_SCOPE_AGENT) - POISON;
  __syncthreads();
  const unsigned int rank = srank;
  if (rank < (unsigned int)(NB - KLAST)) return;   // early blocks retire

  // ---- bounded spin until all NB increments observed ----
  if (tid == 0) {
    for (long it = 0; it < 4000000L; ++it) {   // ~1 s worst case, never hangs
      if (__hip_atomic_load(cnt, __ATOMIC_ACQUIRE, __HIP_MEMORY_SCOPE_AGENT)
          == POISON + (unsigned int)NB) break;
      __builtin_amdgcn_s_sleep(16);
    }
  }
  __syncthreads();

  // ---- phase 2: chunk of 128 entries ----
  const int chunk = (int)(rank - (unsigned int)(NB - KLAST));  // [0,128)
  const int e = chunk * 128 + (tid & 127);   // Gram entry index
  const int pg = tid >> 7;                   // 0..3 partial-group
  float sa = 0.f, sb = 0.f;
#pragma unroll 8
  for (int q = pg; q < PP; q += 4) {
    sa += apart[(size_t)q * (DD * DD) + e];
    sb += bpart[(size_t)q * (DD * DD) + e];
  }
  sA[pg][tid & 127] = sa;
  sB[pg][tid & 127] = sb;
  __syncthreads();

  double pr = 0.0;
  if (tid < 128) {
    float ta = sA[0][tid] + sA[1][tid] + sA[2][tid] + sA[3][tid];
    float tb = sB[0][tid] + sB[1][tid] + sB[2][tid] + sB[3][tid];
    pr = (double)ta * (double)tb;
#pragma unroll
    for (int off = 32; off > 0; off >>= 1)
      pr += __shfl_down(pr, off, 64);
    if ((tid & 63) == 0) dcomb[tid >> 6][0] = pr;
  }
  __syncthreads();
  if (tid == 0) {
    prod[chunk] = dcomb[0][0] + dcomb[1][0];   // plain store
    __threadfence();
    unsigned int r2 = __hip_atomic_fetch_add(cnt2, 1u, __ATOMIC_ACQ_REL,
                                             __HIP_MEMORY_SCOPE_AGENT) - POISON;
    winner = (r2 == (unsigned int)(KLAST - 1));
  }
  __syncthreads();

  // ---- final: elected block reduces 128 prods + 128 diag slots ----
  if (winner) {
    double S = 0.0, t1 = 0.0, t2 = 0.0;
    if (tid < 128) { S = prod[tid]; t1 = ds1[tid]; t2 = ds2[tid]; }
#pragma unroll
    for (int off = 32; off > 0; off >>= 1) {
      S  += __shfl_down(S, off, 64);
      t1 += __shfl_down(t1, off, 64);
      t2 += __shfl_down(t2, off, 64);
    }
    if (tid < 128 && (tid & 63) == 0) {
      dcomb[tid >> 6][0] = S; dcomb[tid >> 6][1] = t1; dcomb[tid >> 6][2] = t2;
    }
    __syncthreads();
    if (tid == 0) {
      double Sf = dcomb[0][0] + dcomb[1][0];
      double d1 = dcomb[0][1] + dcomb[1][1];
      double d2 = dcomb[0][2] + dcomb[1][2];
      double loss = (Sf - d2) / ((double)N * (double)(N - 1)) - (2.0 / N) * d1;
      out[0] = (float)loss;
    }
  }
}

extern "C" void kernel_launch(void* const* d_in, const int* in_sizes, int n_in,
                              void* d_out, int out_size, void* d_ws, size_t ws_size,
                              hipStream_t stream) {
  const float* x = (const float*)d_in[0];
  const float* y = (const float*)d_in[1];
  float* out = (float*)d_out;
  const int N = in_sizes[0] / DD;  // 8192

  char* w = (char*)d_ws;
  float* apart = (float*)w;                              w += (size_t)PP * DD * DD * 4;
  float* bpart = (float*)w;                              w += (size_t)PP * DD * DD * 4;
  double* ds1  = (double*)w;                             w += PP * 8;
  double* ds2  = (double*)w;                             w += PP * 8;
  double* prod = (double*)w;                             w += KLAST * 8;
  unsigned int* cnt  = (unsigned int*)w;                 w += 64;   // own cacheline
  unsigned int* cnt2 = (unsigned int*)w;

  fused_kernel<<<NB, 512, 0, stream>>>(x, y, apart, bpart, ds1, ds2, prod,
                                       cnt, cnt2, out, N);
}

// Round 11
// 72.663 us; speedup vs baseline: 1.8992x; 1.8992x over previous
//
#include <hip/hip_runtime.h>

#define DD 128   // feature dim
#define SR 72    // LDS row stride in bf16 units (64 + 8 pad, bank-spread)
#define PP 128   // partial tiles per matrix
#define NB (2*PP)

typedef float f32x4 __attribute__((ext_vector_type(4)));
typedef short s16x8 __attribute__((ext_vector_type(8)));

// ---------------------------------------------------------------------------
// MAXIMALLY DEFENSIVE STRUCTURE: three dispatches, NO atomics, NO fences,
// NO cross-block communication. All inter-block data flow crosses a
// stream-ordered kernel boundary. (R9/R10 post-mortem: identical-to-R7 code
// with a ticket finish failed the container twice; this isolates whether the
// cross-block ticket was implicated or infra is broken outright.)
//
// Dispatch 1: per-block partial Gram tiles A_p = Xslab^T Xslab (blk<PP) or
// B_p = Yslab^T Yslab via bf16 hi/lo-split MFMA (G = Xh'Xh + Xh'Xl + Xl'Xh,
// ll dropped, ~2^-15 relative). 64-row slab staged TRANSPOSED in LDS
// (Xt[feat][k], 16 B-contiguous in k for both A- and B-fragments; C/D layout
// m89-verified: col = lane&15, row = (lane>>4)*4 + reg).
// X-blocks fold diag sums s1 = sum<x_i,y_i>, s2 = sum<..>^2 from the
// original fp32 registers -> plain stores into per-block slots (no memset).
// ---------------------------------------------------------------------------
__global__ __launch_bounds__(512)
void gram_kernel(const float* __restrict__ x, const float* __restrict__ y,
                 float* __restrict__ apart, float* __restrict__ bpart,
                 double* __restrict__ ds1, double* __restrict__ ds2, int N)
{
  const int blk = blockIdx.x;
  const bool isX = blk < PP;
  const int p = isX ? blk : blk - PP;
  const float* __restrict__ src = isX ? x : y;
  const int slab = N / PP;       // 64
  const int row0 = p * slab;

  __shared__ __align__(16) unsigned short sh_hi[DD * SR];  // 18.4 KB
  __shared__ __align__(16) unsigned short sh_lo[DD * SR];  // 18.4 KB
  __shared__ double wred[8][2];

  const int tid = threadIdx.x;
  const int wave = tid >> 6, lane = tid & 63;
  const int rloc = tid >> 3;     // row within 64-row chunk
  const int fg = tid & 7;        // float4 group within row

  f32x4 acc[8];
#pragma unroll
  for (int t = 0; t < 8; ++t)
#pragma unroll
    for (int k = 0; k < 4; ++k) acc[t][k] = 0.f;

  double s1 = 0.0, s2 = 0.0;

  {
    const float* cb = src + (size_t)row0 * DD;
    const float4* rowp = (const float4*)(cb + rloc * DD);
    float4 v0 = rowp[fg], v1 = rowp[fg + 8], v2 = rowp[fg + 16], v3 = rowp[fg + 24];

    if (isX) {
      const float4* yrp = (const float4*)(y + (size_t)row0 * DD + rloc * DD);
      float4 w0 = yrp[fg], w1 = yrp[fg + 8], w2 = yrp[fg + 16], w3 = yrp[fg + 24];
      float d = v0.x*w0.x + v0.y*w0.y + v0.z*w0.z + v0.w*w0.w
              + v1.x*w1.x + v1.y*w1.y + v1.z*w1.z + v1.w*w1.w
              + v2.x*w2.x + v2.y*w2.y + v2.z*w2.z + v2.w*w2.w
              + v3.x*w3.x + v3.y*w3.y + v3.z*w3.z + v3.w*w3.w;
      d += __shfl_down(d, 4, 8);
      d += __shfl_down(d, 2, 8);
      d += __shfl_down(d, 1, 8);
      if (fg == 0) { s1 += (double)d; s2 += (double)d * (double)d; }
    }

    {
      float vals[16] = {v0.x, v0.y, v0.z, v0.w, v1.x, v1.y, v1.z, v1.w,
                        v2.x, v2.y, v2.z, v2.w, v3.x, v3.y, v3.z, v3.w};
#pragma unroll
      for (int j = 0; j < 4; ++j)
#pragma unroll
        for (int cc = 0; cc < 4; ++cc) {
          const int m = ((fg + (j << 3)) << 2) + cc;
          const float vv = vals[j * 4 + cc];
          const unsigned int b = __float_as_uint(vv);
          const unsigned short hb = (unsigned short)(b >> 16);
          const float hf = __uint_as_float(b & 0xffff0000u);
          const float lf = vv - hf;
          const unsigned short lb = (unsigned short)(__float_as_uint(lf) >> 16);
          sh_hi[m * SR + rloc] = hb;
          sh_lo[m * SR + rloc] = lb;
        }
    }
    __syncthreads();

#pragma unroll
    for (int kb = 0; kb < 64; kb += 32) {
      const int ko = kb + ((lane >> 4) << 3);
      const int arow = (wave * 16 + (lane & 15)) * SR + ko;
      const s16x8 ahi = *(const s16x8*)&sh_hi[arow];
      const s16x8 alo = *(const s16x8*)&sh_lo[arow];
#pragma unroll
      for (int t = 0; t < 8; ++t) {
        const int brow = (t * 16 + (lane & 15)) * SR + ko;
        const s16x8 bhi = *(const s16x8*)&sh_hi[brow];
        const s16x8 blo = *(const s16x8*)&sh_lo[brow];
        acc[t] = __builtin_amdgcn_mfma_f32_16x16x32_bf16(ahi, bhi, acc[t], 0, 0, 0);
        acc[t] = __builtin_amdgcn_mfma_f32_16x16x32_bf16(ahi, blo, acc[t], 0, 0, 0);
        acc[t] = __builtin_amdgcn_mfma_f32_16x16x32_bf16(alo, bhi, acc[t], 0, 0, 0);
      }
    }
  }

  // write private partial tile (C/D layout: col = lane&15, row = (lane>>4)*4+reg)
  float* __restrict__ dst = (isX ? apart : bpart) + (size_t)p * (DD * DD);
  const int col = lane & 15;
  const int rb = (lane >> 4) << 2;
#pragma unroll
  for (int t = 0; t < 8; ++t)
#pragma unroll
    for (int rg = 0; rg < 4; ++rg)
      dst[(wave * 16 + rb + rg) * DD + t * 16 + col] = acc[t][rg];

  if (isX) {
    // diag partials live on lanes 0,8,...,56 of each wave
    s1 += __shfl_down(s1, 32, 64); s2 += __shfl_down(s2, 32, 64);
    s1 += __shfl_down(s1, 16, 64); s2 += __shfl_down(s2, 16, 64);
    s1 += __shfl_down(s1, 8, 64);  s2 += __shfl_down(s2, 8, 64);
    if (lane == 0) { wred[wave][0] = s1; wred[wave][1] = s2; }
    __syncthreads();
    if (tid == 0) {
      double t1 = 0.0, t2 = 0.0;
#pragma unroll
      for (int g = 0; g < 8; ++g) { t1 += wred[g][0]; t2 += wred[g][1]; }
      ds1[p] = t1;   // plain stores, no init required
      ds2[p] = t2;
    }
  }
}

// ---------------------------------------------------------------------------
// Dispatch 2: per-block partial dot. Block owns 64 (a,b) entries; wave w
// sums partials p ≡ w (mod 4) (coalesced), LDS combine, 64-wide shuffle
// reduce -> prod[blk] plain store. No atomics, no finish here.
// ---------------------------------------------------------------------------
__global__ __launch_bounds__(256)
void dot_kernel(const float* __restrict__ apart, const float* __restrict__ bpart,
                double* __restrict__ prod)
{
  const int w = threadIdx.x >> 6, lane = threadIdx.x & 63;
  const int e = blockIdx.x * 64 + lane;  // [0, 16384)
  float sa = 0.f, sb = 0.f;
#pragma unroll 8
  for (int p = w; p < PP; p += 4) {
    sa += apart[(size_t)p * (DD * DD) + e];
    sb += bpart[(size_t)p * (DD * DD) + e];
  }
  __shared__ float sA[4][64], sB[4][64];
  sA[w][lane] = sa;
  sB[w][lane] = sb;
  __syncthreads();
  if (w == 0) {
    float ta = sA[0][lane] + sA[1][lane] + sA[2][lane] + sA[3][lane];
    float tb = sB[0][lane] + sB[1][lane] + sB[2][lane] + sB[3][lane];
    double pr = (double)ta * (double)tb;
#pragma unroll
    for (int off = 32; off > 0; off >>= 1)
      pr += __shfl_down(pr, off, 64);
    if (lane == 0) prod[blockIdx.x] = pr;   // plain store
  }
}

// ---------------------------------------------------------------------------
// Dispatch 3: one block reduces 256 prods + 128 ds1/ds2 slots (double) and
// writes loss = (S - s2)/(N(N-1)) - (2/N)*s1.
// ---------------------------------------------------------------------------
__global__ __launch_bounds__(256)
void finish_kernel(const double* __restrict__ prod,
                   const double* __restrict__ ds1, const double* __restrict__ ds2,
                   float* __restrict__ out, int N)
{
  const int tid = threadIdx.x;
  const int wv = tid >> 6, lane = tid & 63;
  __shared__ double red[4][3];

  double S = prod[tid];                       // 256 entries
  double t1 = (tid < PP) ? ds1[tid] : 0.0;    // 128 entries
  double t2 = (tid < PP) ? ds2[tid] : 0.0;
#pragma unroll
  for (int off = 32; off > 0; off >>= 1) {
    S  += __shfl_down(S, off, 64);
    t1 += __shfl_down(t1, off, 64);
    t2 += __shfl_down(t2, off, 64);
  }
  if (lane == 0) { red[wv][0] = S; red[wv][1] = t1; red[wv][2] = t2; }
  __syncthreads();
  if (tid == 0) {
    double Sf = red[0][0] + red[1][0] + red[2][0] + red[3][0];
    double d1 = red[0][1] + red[1][1] + red[2][1] + red[3][1];
    double d2 = red[0][2] + red[1][2] + red[2][2] + red[3][2];
    double loss = (Sf - d2) / ((double)N * (double)(N - 1)) - (2.0 / N) * d1;
    out[0] = (float)loss;
  }
}

extern "C" void kernel_launch(void* const* d_in, const int* in_sizes, int n_in,
                              void* d_out, int out_size, void* d_ws, size_t ws_size,
                              hipStream_t stream) {
  const float* x = (const float*)d_in[0];
  const float* y = (const float*)d_in[1];
  float* out = (float*)d_out;
  const int N = in_sizes[0] / DD;  // 8192

  char* w = (char*)d_ws;
  float* apart = (float*)w;                              w += (size_t)PP * DD * DD * 4;
  float* bpart = (float*)w;                              w += (size_t)PP * DD * DD * 4;
  double* ds1  = (double*)w;                             w += PP * 8;
  double* ds2  = (double*)w;                             w += PP * 8;
  double* prod = (double*)w;

  gram_kernel<<<NB, 512, 0, stream>>>(x, y, apart, bpart, ds1, ds2, N);
  dot_kernel<<<(DD * DD) / 64, 256, 0, stream>>>(apart, bpart, prod);
  finish_kernel<<<1, 256, 0, stream>>>(prod, ds1, ds2, out, N);
}